// Round 9
// baseline (406.236 us; speedup 1.0000x reference)
//
#include <hip/hip_runtime.h>
#include <hip/hip_bf16.h>

typedef __attribute__((ext_vector_type(4))) int int4v;

#define TOKENS 8192
#define IN_F   4096
#define OUT_F  4096

// ws layout (bytes):
//   0     : double hdr[2]  (hdr[0]=mean, hdr[1]=scale)
//   1024  : double partials[1024]      (weight sums)
//   9216  : float  xpart[1024]         (per-block |x| max)
//   16384 : int8 q[TOKENS][IN_F]
//   16384 + TOKENS*IN_F: int8 s[OUT_F][IN_F]

__global__ __launch_bounds__(256) void k_pre(const float4* __restrict__ w,
                                             const float4* __restrict__ x,
                                             double* __restrict__ partials,
                                             float* __restrict__ xpart) {
  if (blockIdx.x < 1024) {
    __shared__ double sm[256];
    double s = 0.0;
    const float4* p = w + (size_t)blockIdx.x * 4096;
    for (int i = threadIdx.x; i < 4096; i += 256) {
      float4 v = p[i];
      s += (double)v.x + (double)v.y + (double)v.z + (double)v.w;
    }
    sm[threadIdx.x] = s;
    __syncthreads();
    for (int off = 128; off > 0; off >>= 1) {
      if (threadIdx.x < off) sm[threadIdx.x] += sm[threadIdx.x + off];
      __syncthreads();
    }
    if (threadIdx.x == 0) partials[blockIdx.x] = sm[0];
  } else {
    const int b = blockIdx.x - 1024;
    float m = 0.f;
    const size_t n = (size_t)TOKENS * IN_F / 4;
    for (size_t i = (size_t)b * 256 + threadIdx.x; i < n; i += (size_t)1024 * 256) {
      float4 v = x[i];
      m = fmaxf(m, fmaxf(fmaxf(fabsf(v.x), fabsf(v.y)),
                         fmaxf(fabsf(v.z), fabsf(v.w))));
    }
    __shared__ float smf[256];
    smf[threadIdx.x] = m;
    __syncthreads();
    for (int off = 128; off > 0; off >>= 1) {
      if (threadIdx.x < off) smf[threadIdx.x] = fmaxf(smf[threadIdx.x], smf[threadIdx.x + off]);
      __syncthreads();
    }
    if (threadIdx.x == 0) xpart[b] = smf[0];
  }
}

__global__ __launch_bounds__(256) void k_finalize(double* __restrict__ hdr,
                                                  const double* __restrict__ partials,
                                                  const float* __restrict__ xpart) {
  __shared__ double sm[256];
  __shared__ float smf[256];
  double s = partials[threadIdx.x] + partials[threadIdx.x + 256] +
             partials[threadIdx.x + 512] + partials[threadIdx.x + 768];
  float m = fmaxf(fmaxf(xpart[threadIdx.x], xpart[threadIdx.x + 256]),
                  fmaxf(xpart[threadIdx.x + 512], xpart[threadIdx.x + 768]));
  sm[threadIdx.x] = s;
  smf[threadIdx.x] = m;
  __syncthreads();
  for (int off = 128; off > 0; off >>= 1) {
    if (threadIdx.x < off) {
      sm[threadIdx.x] += sm[threadIdx.x + off];
      smf[threadIdx.x] = fmaxf(smf[threadIdx.x], smf[threadIdx.x + off]);
    }
    __syncthreads();
  }
  if (threadIdx.x == 0) {
    hdr[0] = sm[0] / (double)((size_t)OUT_F * IN_F);   // mean of weight
    hdr[1] = 127.0 / (double)smf[0];                   // absmax scale
  }
}

#define QB_BLK ((TOKENS * IN_F / 4) / 256)
#define TB_BLK ((OUT_F * IN_F / 4) / 256)
__global__ __launch_bounds__(256) void k_quant_tern(const float4* __restrict__ x,
                                                    const float4* __restrict__ w,
                                                    int* __restrict__ q,
                                                    int* __restrict__ sgn,
                                                    const double* __restrict__ hdr) {
  if (blockIdx.x < QB_BLK) {
    const double s = hdr[1];
    size_t i = (size_t)blockIdx.x * 256 + threadIdx.x;
    float4 v = x[i];
    int a = (int)rint(s * (double)v.x);
    int b = (int)rint(s * (double)v.y);
    int c = (int)rint(s * (double)v.z);
    int d = (int)rint(s * (double)v.w);
    q[i] = (a & 255) | ((b & 255) << 8) | ((c & 255) << 16) | ((d & 255) << 24);
  } else {
    const double m = hdr[0];
    size_t i = (size_t)(blockIdx.x - QB_BLK) * 256 + threadIdx.x;
    float4 v = w[i];
    int a = ((double)v.x > m) - ((double)v.x < m);
    int b = ((double)v.y > m) - ((double)v.y < m);
    int c = ((double)v.z > m) - ((double)v.z < m);
    int d = ((double)v.w > m) - ((double)v.w < m);
    sgn[i] = (a & 255) | ((b & 255) << 8) | ((c & 255) << 16) | ((d & 255) << 24);
  }
}

// ---------------------------------------------------------------------------
// int8 GEMM, 256x256 block tile, 4 waves (2M x 2N) of 256 threads, per-wave
// 128x128 output (acc[8][8] = 256 VGPR) at 1 wave/SIMD (__launch_bounds 256,1).
// Ops per LDS byte = 128 (vs 85 at 128x64/wave): per K-tile per CU, MFMA pipe
// = 2612 cyc vs LDS reads 770 cyc -> LDS off the critical path by design.
// Cross-K register pipeline: body(kt) = { stage(kt+3) [8 gloads];
// ds_read tile kt+1 into NEXT frag set [16 reads, register-independent of
// this body's MFMAs -> compiler interleaves under them]; 64 MFMAs on CUR set;
// vmcnt(8) [tile kt+1 landed: 16 outstanding, oldest 8]; s_barrier }.
// Ring-4 LDS 128 KB, stage distance 3, unroll-4 so all buffer indices and
// X/Y register sets are compile-time static (rule #20).
// Safety: reads(j) complete before barrier(j) (compiler lgkm before MFMA that
// consumes them); stage(kt+3) overwrites buf[(kt-1)&3], last read two
// barriers earlier. XOR swizzle (verified 0-conflict) on both sides (#21).
// ---------------------------------------------------------------------------
__global__ __launch_bounds__(256, 1) void k_gemm(const signed char* __restrict__ q,
                                                 const signed char* __restrict__ s,
                                                 float* __restrict__ out) {
  __shared__ signed char sA[4][256 * 64];   // 64 KB
  __shared__ signed char sB[4][256 * 64];   // 64 KB
  const int tid  = threadIdx.x;
  const int lane = tid & 63;
  const int wid  = tid >> 6;     // 0..3
  const int wm   = wid >> 1;     // 0..1 -> row offset wm*128
  const int wn   = wid & 1;      // 0..1 -> col offset wn*128
  const int l15  = lane & 15, l4 = lane >> 4;

  // XCD-aware swizzle: 512 blocks, 8 XCDs, 64 blocks/XCD chunk (bijective)
  const int swz = (blockIdx.x & 7) * 64 + (blockIdx.x >> 3);
  const int bm = swz >> 4;       // 0..31
  const int bn = swz & 15;       // 0..15
  const size_t row0 = (size_t)bm * 256;
  const size_t col0 = (size_t)bn * 256;

  const int lane_off = l15 * 64 + ((l4 ^ ((l15 >> 1) & 3)) << 4);

#define STAGE_TILE(KT, BUF)                                                     \
  do {                                                                          \
    const int kt_ = (KT);                                                       \
    _Pragma("unroll")                                                           \
    for (int u = 0; u < 4; ++u) {                                               \
      const int slot = u * 256 + tid;                                           \
      const int r = slot >> 2, sir = slot & 3;                                  \
      const int koff = ((sir ^ ((r >> 1) & 3)) << 4);                           \
      __builtin_amdgcn_global_load_lds(                                         \
          (const __attribute__((address_space(1))) void*)(q + (row0 + (size_t)r) * IN_F + kt_ * 64 + koff), \
          (__attribute__((address_space(3))) void*)(sA[BUF] + (u * 256 + wid * 64) * 16), 16, 0, 0); \
    }                                                                           \
    _Pragma("unroll")                                                           \
    for (int u = 0; u < 4; ++u) {                                               \
      const int slot = u * 256 + tid;                                           \
      const int r = slot >> 2, sir = slot & 3;                                  \
      const int koff = ((sir ^ ((r >> 1) & 3)) << 4);                           \
      __builtin_amdgcn_global_load_lds(                                         \
          (const __attribute__((address_space(1))) void*)(s + (col0 + (size_t)r) * IN_F + kt_ * 64 + koff), \
          (__attribute__((address_space(3))) void*)(sB[BUF] + (u * 256 + wid * 64) * 16), 16, 0, 0); \
    }                                                                           \
  } while (0)

#define READ_TILE(BUF, AV, BV)                                                  \
  do {                                                                          \
    _Pragma("unroll")                                                           \
    for (int f = 0; f < 8; ++f)                                                 \
      AV[f] = *(const int4v*)(sA[BUF] + (wm * 128 + f * 16) * 64 + lane_off);   \
    _Pragma("unroll")                                                           \
    for (int f = 0; f < 8; ++f)                                                 \
      BV[f] = *(const int4v*)(sB[BUF] + (wn * 128 + f * 16) * 64 + lane_off);   \
  } while (0)

#define MFMA_TILE(AV, BV)                                                       \
  do {                                                                          \
    _Pragma("unroll")                                                           \
    for (int m_ = 0; m_ < 8; ++m_)                                              \
      _Pragma("unroll")                                                         \
      for (int n_ = 0; n_ < 8; ++n_)                                            \
        acc[m_][n_] = __builtin_amdgcn_mfma_i32_16x16x64_i8(AV[m_], BV[n_],     \
                                                            acc[m_][n_], 0, 0, 0); \
  } while (0)

#define ENDBODY()                                                               \
  do {                                                                          \
    __builtin_amdgcn_sched_barrier(0);                                          \
    asm volatile("s_waitcnt vmcnt(8)" ::: "memory");                            \
    __builtin_amdgcn_s_barrier();                                               \
    __builtin_amdgcn_sched_barrier(0);                                          \
  } while (0)

  int4v acc[8][8];
#pragma unroll
  for (int i = 0; i < 8; ++i)
#pragma unroll
    for (int j = 0; j < 8; ++j) acc[i][j] = int4v{0, 0, 0, 0};

  int4v aX[8], bX[8], aY[8], bY[8];

  // prologue: stage tiles 0,1,2 (24 gloads); vmcnt(8) -> tiles 0 AND 1 landed
  STAGE_TILE(0, 0);
  STAGE_TILE(1, 1);
  STAGE_TILE(2, 2);
  __builtin_amdgcn_sched_barrier(0);
  asm volatile("s_waitcnt vmcnt(8)" ::: "memory");
  __builtin_amdgcn_s_barrier();
  __builtin_amdgcn_sched_barrier(0);
  READ_TILE(0, aX, bX);

  for (int kt = 0; kt < 64; kt += 4) {
    // body kt+0: MFMA tile kt (X, buf0), read kt+1 (buf1 -> Y), stage kt+3 -> buf3
    STAGE_TILE((kt + 3) & 63, 3);
    READ_TILE(1, aY, bY);
    MFMA_TILE(aX, bX);
    ENDBODY();
    // body kt+1: MFMA kt+1 (Y, buf1), read kt+2 (buf2 -> X), stage kt+4 -> buf0
    STAGE_TILE((kt + 4) & 63, 0);
    READ_TILE(2, aX, bX);
    MFMA_TILE(aY, bY);
    ENDBODY();
    // body kt+2: MFMA kt+2 (X, buf2), read kt+3 (buf3 -> Y), stage kt+5 -> buf1
    STAGE_TILE((kt + 5) & 63, 1);
    READ_TILE(3, aY, bY);
    MFMA_TILE(aX, bX);
    ENDBODY();
    // body kt+3: MFMA kt+3 (Y, buf3), read kt+4 (buf0 -> X), stage kt+6 -> buf2
    STAGE_TILE((kt + 6) & 63, 2);
    READ_TILE(0, aX, bX);
    MFMA_TILE(aY, bY);
    ENDBODY();
  }

  // epilogue: C/D mapping col = lane&15, row = (lane>>4)*4 + r
#pragma unroll
  for (int m = 0; m < 8; ++m)
#pragma unroll
    for (int n = 0; n < 8; ++n)
#pragma unroll
      for (int r = 0; r < 4; ++r) {
        const size_t rg = row0 + wm * 128 + m * 16 + l4 * 4 + r;
        const size_t cg = col0 + wn * 128 + n * 16 + l15;
        out[rg * OUT_F + cg] = (float)acc[m][n][r];
      }

#undef STAGE_TILE
#undef READ_TILE
#undef MFMA_TILE
#undef ENDBODY
}

extern "C" void kernel_launch(void* const* d_in, const int* in_sizes, int n_in,
                              void* d_out, int out_size, void* d_ws, size_t ws_size,
                              hipStream_t stream) {
  const float* x = (const float*)d_in[0];   // input  [8192][4096] f32
  const float* w = (const float*)d_in[1];   // weight [4096][4096] f32
  float* out = (float*)d_out;               // [8192][4096] f32

  char* ws = (char*)d_ws;
  double*   hdr      = (double*)ws;
  double*   partials = (double*)(ws + 1024);
  float*    xpart    = (float*)(ws + 9216);
  signed char* qbuf  = (signed char*)(ws + 16384);
  signed char* sbuf  = (signed char*)(ws + 16384 + (size_t)TOKENS * IN_F);

  k_pre<<<2048, 256, 0, stream>>>((const float4*)w, (const float4*)x, partials, xpart);
  k_finalize<<<1, 256, 0, stream>>>(hdr, partials, xpart);
  k_quant_tern<<<QB_BLK + TB_BLK, 256, 0, stream>>>((const float4*)x, (const float4*)w,
                                                    (int*)qbuf, (int*)sbuf, hdr);
  k_gemm<<<(TOKENS / 256) * (OUT_F / 256), 256, 0, stream>>>(qbuf, sbuf, out);
}

// Round 10
// 240.912 us; speedup vs baseline: 1.6862x; 1.6862x over previous
//
#include <hip/hip_runtime.h>
#include <hip/hip_bf16.h>

typedef __attribute__((ext_vector_type(4))) int int4v;

#define TOKENS 8192
#define IN_F   4096
#define OUT_F  4096
#define NKT    64              // K-tiles of 64 B
#define NNF    (OUT_F / 16)    // 256 B-fragments per K-tile

// ws layout (bytes):
//   0     : double hdr[2]  (hdr[0]=mean, hdr[1]=scale)
//   1024  : double partials[1024]
//   9216  : float  xpart[1024]
//   16384 : int8 q[TOKENS][IN_F] row-major           (33.55 MB)
//   16384+TOKENS*IN_F : B' fragment-major [NKT][NNF][1024 B]  (16.78 MB)

__global__ __launch_bounds__(256) void k_pre(const float4* __restrict__ w,
                                             const float4* __restrict__ x,
                                             double* __restrict__ partials,
                                             float* __restrict__ xpart) {
  if (blockIdx.x < 1024) {
    __shared__ double sm[256];
    double s = 0.0;
    const float4* p = w + (size_t)blockIdx.x * 4096;
    for (int i = threadIdx.x; i < 4096; i += 256) {
      float4 v = p[i];
      s += (double)v.x + (double)v.y + (double)v.z + (double)v.w;
    }
    sm[threadIdx.x] = s;
    __syncthreads();
    for (int off = 128; off > 0; off >>= 1) {
      if (threadIdx.x < off) sm[threadIdx.x] += sm[threadIdx.x + off];
      __syncthreads();
    }
    if (threadIdx.x == 0) partials[blockIdx.x] = sm[0];
  } else {
    const int b = blockIdx.x - 1024;
    float m = 0.f;
    const size_t n = (size_t)TOKENS * IN_F / 4;
    for (size_t i = (size_t)b * 256 + threadIdx.x; i < n; i += (size_t)1024 * 256) {
      float4 v = x[i];
      m = fmaxf(m, fmaxf(fmaxf(fabsf(v.x), fabsf(v.y)),
                         fmaxf(fabsf(v.z), fabsf(v.w))));
    }
    __shared__ float smf[256];
    smf[threadIdx.x] = m;
    __syncthreads();
    for (int off = 128; off > 0; off >>= 1) {
      if (threadIdx.x < off) smf[threadIdx.x] = fmaxf(smf[threadIdx.x], smf[threadIdx.x + off]);
      __syncthreads();
    }
    if (threadIdx.x == 0) xpart[b] = smf[0];
  }
}

__global__ __launch_bounds__(256) void k_finalize(double* __restrict__ hdr,
                                                  const double* __restrict__ partials,
                                                  const float* __restrict__ xpart) {
  __shared__ double sm[256];
  __shared__ float smf[256];
  double s = partials[threadIdx.x] + partials[threadIdx.x + 256] +
             partials[threadIdx.x + 512] + partials[threadIdx.x + 768];
  float m = fmaxf(fmaxf(xpart[threadIdx.x], xpart[threadIdx.x + 256]),
                  fmaxf(xpart[threadIdx.x + 512], xpart[threadIdx.x + 768]));
  sm[threadIdx.x] = s;
  smf[threadIdx.x] = m;
  __syncthreads();
  for (int off = 128; off > 0; off >>= 1) {
    if (threadIdx.x < off) {
      sm[threadIdx.x] += sm[threadIdx.x + off];
      smf[threadIdx.x] = fmaxf(smf[threadIdx.x], smf[threadIdx.x + off]);
    }
    __syncthreads();
  }
  if (threadIdx.x == 0) {
    hdr[0] = sm[0] / (double)((size_t)OUT_F * IN_F);   // mean of weight
    hdr[1] = 127.0 / (double)smf[0];                   // absmax scale
  }
}

// A: absmax-quantize row-major (for global_load_lds staging).
// B: ternarize + fragment-major pack: chunk c (0..63) of fragment (kt,nf)
// holds row nf*16+(c>>2), k-bytes [kt*64+(c&3)*16, +16). GEMM lane l loads
// chunk (l&15)*4+(l>>4) = its 16x16x64 MFMA B-operand slice (passed in R8).
#define QB_BLK ((TOKENS * IN_F / 4) / 256)
#define B_PACK_BLK ((NKT * NNF * 64) / 256)   // 4096
__global__ __launch_bounds__(256) void k_quant_pack(const float4* __restrict__ x,
                                                    const float4* __restrict__ w,
                                                    int* __restrict__ q,
                                                    int4v* __restrict__ Bp,
                                                    const double* __restrict__ hdr) {
  if (blockIdx.x < QB_BLK) {
    const double s = hdr[1];
    size_t i = (size_t)blockIdx.x * 256 + threadIdx.x;
    float4 v = x[i];
    int a = (int)rint(s * (double)v.x);
    int b = (int)rint(s * (double)v.y);
    int c = (int)rint(s * (double)v.z);
    int d = (int)rint(s * (double)v.w);
    q[i] = (a & 255) | ((b & 255) << 8) | ((c & 255) << 16) | ((d & 255) << 24);
  } else {
    const double m = hdr[0];
    const int gid  = (blockIdx.x - QB_BLK) * 256 + threadIdx.x;
    const int cid  = gid & 63;
    const int frag = gid >> 6;          // kt*NNF + nf
    const int kt   = frag >> 8;
    const int nf   = frag & (NNF - 1);
    const int row  = nf * 16 + (cid >> 2);
    const float4* src = w + (size_t)row * 1024 + kt * 16 + (cid & 3) * 4;
    int o[4];
#pragma unroll
    for (int j = 0; j < 4; ++j) {
      float4 v = src[j];
      int a = ((double)v.x > m) - ((double)v.x < m);
      int b = ((double)v.y > m) - ((double)v.y < m);
      int c = ((double)v.z > m) - ((double)v.z < m);
      int d = ((double)v.w > m) - ((double)v.w < m);
      o[j] = (a & 255) | ((b & 255) << 8) | ((c & 255) << 16) | ((d & 255) << 24);
    }
    Bp[gid] = int4v{o[0], o[1], o[2], o[3]};
  }
}

// ---------------------------------------------------------------------------
// int8 GEMM, 256x256 tile, 8 waves (2M x 4N), per-wave 128x64.
// A: ring-4 LDS (64 KB), global_load_lds, XOR swizzle (0-conflict since R3),
//    stage distance 3. B: direct global->VGPR from fragment-major Bp,
//    register double-buffer distance 1.
// Decoupled pipeline: iter kt issues {b(kt+1) x4, stageA(kt+3) x2,
// ds_read A(kt+1) x8}, then MFMAs tile kt from regs (no wait), then
// vmcnt(2) + lgkm(0) + barrier.
// vmcnt proof (issue order b then stage): outstanding at bottom of kt =
// [stA(kt+2) x2 (from kt-1), b(kt+1) x4, stA(kt+3) x2]; draining b(kt+1)
// drains the older stA(kt+2); vmcnt(2) leaves exactly stA(kt+3) x2.
// => b(kt+1) in regs, A-LDS tile kt+1 landed (stA(kt+1) drained at kt-1).
// Buffer safety: stageA(kt+3)->buf[(kt+3)&3]=buf[(kt-1)&3], whose reads
// (iter kt-2) were drained by lgkm(0) two barriers earlier.
// lgkm(0) after MFMA cluster: the 8 ds_reads complete under MFMA issue.
// ---------------------------------------------------------------------------
__global__ __launch_bounds__(512, 2) void k_gemm(const signed char* __restrict__ q,
                                                 const signed char* __restrict__ Bp,
                                                 float* __restrict__ out) {
  __shared__ signed char sA[4][256 * 64];   // 64 KB
  const int tid  = threadIdx.x;
  const int lane = tid & 63;
  const int wid  = tid >> 6;     // 0..7
  const int wm   = wid >> 2;     // 0..1 -> row offset wm*128
  const int wn   = wid & 3;      // 0..3 -> col offset wn*64
  const int l15  = lane & 15, l4 = lane >> 4;
  const int perm = l15 * 4 + l4;

  // XCD-aware swizzle: 512 blocks, 8 XCDs, 64 blocks/XCD chunk (bijective)
  const int swz = (blockIdx.x & 7) * 64 + (blockIdx.x >> 3);
  const int bm = swz >> 4;       // 0..31
  const int bn = swz & 15;       // 0..15
  const size_t row0 = (size_t)bm * 256;
  const size_t col0 = (size_t)bn * 256;

  const int lane_off = l15 * 64 + ((l4 ^ ((l15 >> 1) & 3)) << 4);
  const signed char* bBase = Bp + ((size_t)(bn * 16 + wn * 4)) * 1024 + perm * 16;

#define STAGE_A(KT, BUF)                                                        \
  do {                                                                          \
    const int kt_ = (KT);                                                       \
    _Pragma("unroll")                                                           \
    for (int u = 0; u < 2; ++u) {                                               \
      const int slot = u * 512 + tid;                                           \
      const int r = slot >> 2, sir = slot & 3;                                  \
      const int koff = ((sir ^ ((r >> 1) & 3)) << 4);                           \
      __builtin_amdgcn_global_load_lds(                                         \
          (const __attribute__((address_space(1))) void*)(q + (row0 + (size_t)r) * IN_F + kt_ * 64 + koff), \
          (__attribute__((address_space(3))) void*)(sA[BUF] + (u * 512 + wid * 64) * 16), 16, 0, 0); \
    }                                                                           \
  } while (0)

#define LOAD_B(KT, BV)                                                          \
  do {                                                                          \
    const size_t o_ = (size_t)(KT) * (NNF * 1024);                              \
    _Pragma("unroll")                                                           \
    for (int n_ = 0; n_ < 4; ++n_)                                              \
      BV[n_] = *(const int4v*)(bBase + o_ + n_ * 1024);                         \
  } while (0)

#define READ_A(BUF, AV)                                                         \
  do {                                                                          \
    _Pragma("unroll")                                                           \
    for (int f = 0; f < 8; ++f)                                                 \
      AV[f] = *(const int4v*)(sA[BUF] + (wm * 128 + f * 16) * 64 + lane_off);   \
  } while (0)

#define MFMA_T(AV, BV)                                                          \
  do {                                                                          \
    _Pragma("unroll")                                                           \
    for (int m_ = 0; m_ < 8; ++m_)                                              \
      _Pragma("unroll")                                                         \
      for (int n_ = 0; n_ < 4; ++n_)                                            \
        acc[m_][n_] = __builtin_amdgcn_mfma_i32_16x16x64_i8(AV[m_], BV[n_],     \
                                                            acc[m_][n_], 0, 0, 0); \
  } while (0)

#define BODY(KT, BUF_RD, BUF_ST, ACUR, BCUR, ANXT, BNXT)                        \
  do {                                                                          \
    LOAD_B(((KT) + 1) & 63, BNXT);                                              \
    STAGE_A(((KT) + 3) & 63, BUF_ST);                                           \
    READ_A(BUF_RD, ANXT);                                                       \
    __builtin_amdgcn_sched_barrier(0);                                          \
    __builtin_amdgcn_s_setprio(1);                                              \
    MFMA_T(ACUR, BCUR);                                                         \
    __builtin_amdgcn_s_setprio(0);                                              \
    __builtin_amdgcn_sched_barrier(0);                                          \
    asm volatile("s_waitcnt vmcnt(2)" ::: "memory");                            \
    asm volatile("s_waitcnt lgkmcnt(0)" ::: "memory");                          \
    __builtin_amdgcn_sched_barrier(0);                                          \
    __builtin_amdgcn_s_barrier();                                               \
    __builtin_amdgcn_sched_barrier(0);                                          \
  } while (0)

  int4v acc[8][4];
#pragma unroll
  for (int i = 0; i < 8; ++i)
#pragma unroll
    for (int j = 0; j < 4; ++j) acc[i][j] = int4v{0, 0, 0, 0};

  int4v aX[8], bX[4], aY[8], bY[4];

  // prologue: b(0); stageA(0); stageA(1); stageA(2) -> vmcnt(2) leaves stA(2)
  LOAD_B(0, bX);
  STAGE_A(0, 0);
  STAGE_A(1, 1);
  STAGE_A(2, 2);
  __builtin_amdgcn_sched_barrier(0);
  asm volatile("s_waitcnt vmcnt(2)" ::: "memory");
  __builtin_amdgcn_s_barrier();
  __builtin_amdgcn_sched_barrier(0);
  READ_A(0, aX);
  asm volatile("s_waitcnt lgkmcnt(0)" ::: "memory");
  __builtin_amdgcn_sched_barrier(0);

  for (int kt = 0; kt < 64; kt += 4) {
    BODY(kt + 0, /*rd*/1, /*st*/3, aX, bX, aY, bY);
    BODY(kt + 1, /*rd*/2, /*st*/0, aY, bY, aX, bX);
    BODY(kt + 2, /*rd*/3, /*st*/1, aX, bX, aY, bY);
    BODY(kt + 3, /*rd*/0, /*st*/2, aY, bY, aX, bX);
  }

  // epilogue: C/D mapping col = lane&15, row = (lane>>4)*4 + r
#pragma unroll
  for (int m = 0; m < 8; ++m)
#pragma unroll
    for (int n = 0; n < 4; ++n)
#pragma unroll
      for (int r = 0; r < 4; ++r) {
        const size_t rg = row0 + wm * 128 + m * 16 + l4 * 4 + r;
        const size_t cg = col0 + wn * 64 + n * 16 + l15;
        out[rg * OUT_F + cg] = (float)acc[m][n][r];
      }

#undef STAGE_A
#undef LOAD_B
#undef READ_A
#undef MFMA_T
#undef BODY
}

extern "C" void kernel_launch(void* const* d_in, const int* in_sizes, int n_in,
                              void* d_out, int out_size, void* d_ws, size_t ws_size,
                              hipStream_t stream) {
  const float* x = (const float*)d_in[0];   // input  [8192][4096] f32
  const float* w = (const float*)d_in[1];   // weight [4096][4096] f32
  float* out = (float*)d_out;               // [8192][4096] f32

  char* ws = (char*)d_ws;
  double*   hdr      = (double*)ws;
  double*   partials = (double*)(ws + 1024);
  float*    xpart    = (float*)(ws + 9216);
  signed char* qbuf  = (signed char*)(ws + 16384);
  signed char* Bpb   = (signed char*)(ws + 16384 + (size_t)TOKENS * IN_F);

  k_pre<<<2048, 256, 0, stream>>>((const float4*)w, (const float4*)x, partials, xpart);
  k_finalize<<<1, 256, 0, stream>>>(hdr, partials, xpart);
  k_quant_pack<<<QB_BLK + B_PACK_BLK, 256, 0, stream>>>((const float4*)x, (const float4*)w,
                                                        (int*)qbuf, (int4v*)Bpb, hdr);
  k_gemm<<<(TOKENS / 256) * (OUT_F / 256), 512, 0, stream>>>(qbuf, Bpb, out);
}

// Round 11
// 223.373 us; speedup vs baseline: 1.8186x; 1.0785x over previous
//
#include <hip/hip_runtime.h>
#include <hip/hip_bf16.h>

typedef __attribute__((ext_vector_type(4))) int int4v;

#define TOKENS 8192
#define IN_F   4096
#define OUT_F  4096

// ws layout (bytes):
//   0     : double hdr[2]  (hdr[0]=mean, hdr[1]=scale)
//   1024  : double partials[1024]
//   9216  : float  xpart[1024]
//   16384 : int8 q[TOKENS][IN_F]
//   16384 + TOKENS*IN_F: int8 s[OUT_F][IN_F]

__global__ __launch_bounds__(256) void k_pre(const float4* __restrict__ w,
                                             const float4* __restrict__ x,
                                             double* __restrict__ partials,
                                             float* __restrict__ xpart) {
  if (blockIdx.x < 1024) {
    __shared__ double sm[256];
    double s = 0.0;
    const float4* p = w + (size_t)blockIdx.x * 4096;
    for (int i = threadIdx.x; i < 4096; i += 256) {
      float4 v = p[i];
      s += (double)v.x + (double)v.y + (double)v.z + (double)v.w;
    }
    sm[threadIdx.x] = s;
    __syncthreads();
    for (int off = 128; off > 0; off >>= 1) {
      if (threadIdx.x < off) sm[threadIdx.x] += sm[threadIdx.x + off];
      __syncthreads();
    }
    if (threadIdx.x == 0) partials[blockIdx.x] = sm[0];
  } else {
    const int b = blockIdx.x - 1024;
    float m = 0.f;
    const size_t n = (size_t)TOKENS * IN_F / 4;
    for (size_t i = (size_t)b * 256 + threadIdx.x; i < n; i += (size_t)1024 * 256) {
      float4 v = x[i];
      m = fmaxf(m, fmaxf(fmaxf(fabsf(v.x), fabsf(v.y)),
                         fmaxf(fabsf(v.z), fabsf(v.w))));
    }
    __shared__ float smf[256];
    smf[threadIdx.x] = m;
    __syncthreads();
    for (int off = 128; off > 0; off >>= 1) {
      if (threadIdx.x < off) smf[threadIdx.x] = fmaxf(smf[threadIdx.x], smf[threadIdx.x + off]);
      __syncthreads();
    }
    if (threadIdx.x == 0) xpart[b] = smf[0];
  }
}

__global__ __launch_bounds__(256) void k_finalize(double* __restrict__ hdr,
                                                  const double* __restrict__ partials,
                                                  const float* __restrict__ xpart) {
  __shared__ double sm[256];
  __shared__ float smf[256];
  double s = partials[threadIdx.x] + partials[threadIdx.x + 256] +
             partials[threadIdx.x + 512] + partials[threadIdx.x + 768];
  float m = fmaxf(fmaxf(xpart[threadIdx.x], xpart[threadIdx.x + 256]),
                  fmaxf(xpart[threadIdx.x + 512], xpart[threadIdx.x + 768]));
  sm[threadIdx.x] = s;
  smf[threadIdx.x] = m;
  __syncthreads();
  for (int off = 128; off > 0; off >>= 1) {
    if (threadIdx.x < off) {
      sm[threadIdx.x] += sm[threadIdx.x + off];
      smf[threadIdx.x] = fmaxf(smf[threadIdx.x], smf[threadIdx.x + off]);
    }
    __syncthreads();
  }
  if (threadIdx.x == 0) {
    hdr[0] = sm[0] / (double)((size_t)OUT_F * IN_F);   // mean of weight
    hdr[1] = 127.0 / (double)smf[0];                   // absmax scale
  }
}

#define QB_BLK ((TOKENS * IN_F / 4) / 256)
#define TB_BLK ((OUT_F * IN_F / 4) / 256)
__global__ __launch_bounds__(256) void k_quant_tern(const float4* __restrict__ x,
                                                    const float4* __restrict__ w,
                                                    int* __restrict__ q,
                                                    int* __restrict__ sgn,
                                                    const double* __restrict__ hdr) {
  if (blockIdx.x < QB_BLK) {
    const double s = hdr[1];
    size_t i = (size_t)blockIdx.x * 256 + threadIdx.x;
    float4 v = x[i];
    int a = (int)rint(s * (double)v.x);
    int b = (int)rint(s * (double)v.y);
    int c = (int)rint(s * (double)v.z);
    int d = (int)rint(s * (double)v.w);
    q[i] = (a & 255) | ((b & 255) << 8) | ((c & 255) << 16) | ((d & 255) << 24);
  } else {
    const double m = hdr[0];
    size_t i = (size_t)(blockIdx.x - QB_BLK) * 256 + threadIdx.x;
    float4 v = w[i];
    int a = ((double)v.x > m) - ((double)v.x < m);
    int b = ((double)v.y > m) - ((double)v.y < m);
    int c = ((double)v.z > m) - ((double)v.z < m);
    int d = ((double)v.w > m) - ((double)v.w < m);
    sgn[i] = (a & 255) | ((b & 255) << 8) | ((c & 255) << 16) | ((d & 255) << 24);
  }
}

// ---------------------------------------------------------------------------
// int8 GEMM, 256x256 tile, BK=64B, ring-4 LDS (128 KB), 8 waves 2Mx4N,
// per-wave 128x64. R3 geometry + CROSS-PHASE READ PIPELINING (derived waits):
// every phase's ds_reads are issued one phase EARLY, waited with a counted
// lgkmcnt that drains only the prior batch -> read port time hides under the
// MFMA clusters instead of preceding them.
// Schedule per K-tile kt (X/Y = a-reg alternation by kt parity):
//  P0: issue b23(kt) reads[2]; stage-A(kt+3)[2 vm]; barrier;
//      lgkmcnt(2)  [drains a(kt)x8+b01(kt) issued in P1(kt-1); leaves b23];
//      16 MFMA a(kt)xb01(kt);
//      vmcnt(6)    [outstanding 10: A/B(kt+1),A/B(kt+2),A(kt+3) -> drain 4
//                   oldest = tile kt+1 fully in LDS]; barrier.
//  P1: issue a(kt+1)[8]+b01(kt+1)[2] reads from buf[(kt+1)&3] (safe: landed);
//      stage-B(kt+3)[2 vm]; barrier;
//      lgkmcnt(10) [drains only b23(kt)];
//      16 MFMA a(kt)xb23(kt); barrier.
// Buffer safety: stage(kt+3) -> buf[(kt-1)&3]; its tile-(kt-1) reads were
// drained by P0(kt)'s lgkmcnt(2) chain one barrier earlier. b01/b23 share
// regs across tiles (consumed before re-read issues, in-order per wave).
// Rule #18: sched_barrier(0) after every counted wait.
// ---------------------------------------------------------------------------
__global__ __launch_bounds__(512, 2) void k_gemm(const signed char* __restrict__ q,
                                                 const signed char* __restrict__ s,
                                                 float* __restrict__ out) {
  __shared__ signed char sA[4][256 * 64];   // 64 KB
  __shared__ signed char sB[4][256 * 64];   // 64 KB
  const int tid  = threadIdx.x;
  const int lane = tid & 63;
  const int wid  = tid >> 6;     // 0..7
  const int wm   = wid >> 2;     // 0..1 -> row offset wm*128
  const int wn   = wid & 3;      // 0..3 -> col offset wn*64
  const int l15  = lane & 15, l4 = lane >> 4;

  // XCD-aware swizzle: 512 blocks, 8 XCDs, 64 blocks/XCD chunk (bijective)
  const int swz = (blockIdx.x & 7) * 64 + (blockIdx.x >> 3);
  const int bm = swz >> 4;       // 0..31
  const int bn = swz & 15;       // 0..15
  const size_t row0 = (size_t)bm * 256;
  const size_t col0 = (size_t)bn * 256;

  const int lane_off = l15 * 64 + ((l4 ^ ((l15 >> 1) & 3)) << 4);

#define STAGE_A(KT, BUF)                                                        \
  do {                                                                          \
    const int kt_ = (KT);                                                       \
    _Pragma("unroll")                                                           \
    for (int u = 0; u < 2; ++u) {                                               \
      const int slot = u * 512 + tid;                                           \
      const int r = slot >> 2, sir = slot & 3;                                  \
      const int koff = ((sir ^ ((r >> 1) & 3)) << 4);                           \
      __builtin_amdgcn_global_load_lds(                                         \
          (const __attribute__((address_space(1))) void*)(q + (row0 + (size_t)r) * IN_F + kt_ * 64 + koff), \
          (__attribute__((address_space(3))) void*)(sA[BUF] + (u * 512 + wid * 64) * 16), 16, 0, 0); \
    }                                                                           \
  } while (0)

#define STAGE_B(KT, BUF)                                                        \
  do {                                                                          \
    const int kt_ = (KT);                                                       \
    _Pragma("unroll")                                                           \
    for (int u = 0; u < 2; ++u) {                                               \
      const int slot = u * 512 + tid;                                           \
      const int r = slot >> 2, sir = slot & 3;                                  \
      const int koff = ((sir ^ ((r >> 1) & 3)) << 4);                           \
      __builtin_amdgcn_global_load_lds(                                         \
          (const __attribute__((address_space(1))) void*)(s + (col0 + (size_t)r) * IN_F + kt_ * 64 + koff), \
          (__attribute__((address_space(3))) void*)(sB[BUF] + (u * 512 + wid * 64) * 16), 16, 0, 0); \
    }                                                                           \
  } while (0)

#define READ_A8(BUF, AV)                                                        \
  do {                                                                          \
    _Pragma("unroll")                                                           \
    for (int f = 0; f < 8; ++f)                                                 \
      AV[f] = *(const int4v*)(sA[BUF] + (wm * 128 + f * 16) * 64 + lane_off);   \
  } while (0)

#define READ_B01(BUF)                                                           \
  do {                                                                          \
    b01[0] = *(const int4v*)(sB[BUF] + (wn * 64 +  0) * 64 + lane_off);         \
    b01[1] = *(const int4v*)(sB[BUF] + (wn * 64 + 16) * 64 + lane_off);         \
  } while (0)

#define READ_B23(BUF)                                                           \
  do {                                                                          \
    b23[0] = *(const int4v*)(sB[BUF] + (wn * 64 + 32) * 64 + lane_off);         \
    b23[1] = *(const int4v*)(sB[BUF] + (wn * 64 + 48) * 64 + lane_off);         \
  } while (0)

#define MFMA16(AV, BV, NB)                                                      \
  do {                                                                          \
    _Pragma("unroll")                                                           \
    for (int m_ = 0; m_ < 8; ++m_) {                                            \
      acc[m_][NB]     = __builtin_amdgcn_mfma_i32_16x16x64_i8(AV[m_], BV[0],    \
                                                              acc[m_][NB], 0, 0, 0); \
      acc[m_][NB + 1] = __builtin_amdgcn_mfma_i32_16x16x64_i8(AV[m_], BV[1],    \
                                                              acc[m_][NB + 1], 0, 0, 0); \
    }                                                                           \
  } while (0)

#define SB0() __builtin_amdgcn_sched_barrier(0)

#define PHASE0(KT, RB, SBUF, AC)                                                \
  do {                                                                          \
    READ_B23(RB);                                                               \
    STAGE_A(((KT) + 3) & 63, SBUF);                                             \
    SB0();                                                                      \
    __builtin_amdgcn_s_barrier();                                               \
    asm volatile("s_waitcnt lgkmcnt(2)" ::: "memory");                          \
    SB0();                                                                      \
    __builtin_amdgcn_s_setprio(1);                                              \
    MFMA16(AC, b01, 0);                                                         \
    __builtin_amdgcn_s_setprio(0);                                              \
    SB0();                                                                      \
    asm volatile("s_waitcnt vmcnt(6)" ::: "memory");                            \
    SB0();                                                                      \
    __builtin_amdgcn_s_barrier();                                               \
    SB0();                                                                      \
  } while (0)

#define PHASE1(KT, NB, SBUF, AC, AN)                                            \
  do {                                                                          \
    READ_A8(NB, AN);                                                            \
    READ_B01(NB);                                                               \
    STAGE_B(((KT) + 3) & 63, SBUF);                                             \
    SB0();                                                                      \
    __builtin_amdgcn_s_barrier();                                               \
    asm volatile("s_waitcnt lgkmcnt(10)" ::: "memory");                         \
    SB0();                                                                      \
    __builtin_amdgcn_s_setprio(1);                                              \
    MFMA16(AC, b23, 2);                                                         \
    __builtin_amdgcn_s_setprio(0);                                              \
    SB0();                                                                      \
    __builtin_amdgcn_s_barrier();                                               \
    SB0();                                                                      \
  } while (0)

  int4v acc[8][4];
#pragma unroll
  for (int i = 0; i < 8; ++i)
#pragma unroll
    for (int j = 0; j < 4; ++j) acc[i][j] = int4v{0, 0, 0, 0};

  int4v aX[8], aY[8], b01[2], b23[2];

  // prologue: stage tiles 0,1,2 (12 vm loads); vmcnt(8) drains tile 0's 4.
  STAGE_A(0, 0); STAGE_B(0, 0);
  STAGE_A(1, 1); STAGE_B(1, 1);
  STAGE_A(2, 2); STAGE_B(2, 2);
  SB0();
  asm volatile("s_waitcnt vmcnt(8)" ::: "memory");
  __builtin_amdgcn_s_barrier();
  SB0();
  READ_A8(0, aX);
  READ_B01(0);
  SB0();

  for (int kt = 0; kt < 64; kt += 4) {
    PHASE0(kt + 0, 0, 3, aX);  PHASE1(kt + 0, 1, 3, aX, aY);
    PHASE0(kt + 1, 1, 0, aY);  PHASE1(kt + 1, 2, 0, aY, aX);
    PHASE0(kt + 2, 2, 1, aX);  PHASE1(kt + 2, 3, 1, aX, aY);
    PHASE0(kt + 3, 3, 2, aY);  PHASE1(kt + 3, 0, 2, aY, aX);
  }

  // epilogue: C/D mapping col = lane&15, row = (lane>>4)*4 + r
#pragma unroll
  for (int m = 0; m < 8; ++m)
#pragma unroll
    for (int n = 0; n < 4; ++n)
#pragma unroll
      for (int r = 0; r < 4; ++r) {
        const size_t rg = row0 + wm * 128 + m * 16 + l4 * 4 + r;
        const size_t cg = col0 + wn * 64 + n * 16 + l15;
        out[rg * OUT_F + cg] = (float)acc[m][n][r];
      }

#undef STAGE_A
#undef STAGE_B
#undef READ_A8
#undef READ_B01
#undef READ_B23
#undef MFMA16
#undef PHASE0
#undef PHASE1
#undef SB0
}

extern "C" void kernel_launch(void* const* d_in, const int* in_sizes, int n_in,
                              void* d_out, int out_size, void* d_ws, size_t ws_size,
                              hipStream_t stream) {
  const float* x = (const float*)d_in[0];   // input  [8192][4096] f32
  const float* w = (const float*)d_in[1];   // weight [4096][4096] f32
  float* out = (float*)d_out;               // [8192][4096] f32

  char* ws = (char*)d_ws;
  double*   hdr      = (double*)ws;
  double*   partials = (double*)(ws + 1024);
  float*    xpart    = (float*)(ws + 9216);
  signed char* qbuf  = (signed char*)(ws + 16384);
  signed char* sbuf  = (signed char*)(ws + 16384 + (size_t)TOKENS * IN_F);

  k_pre<<<2048, 256, 0, stream>>>((const float4*)w, (const float4*)x, partials, xpart);
  k_finalize<<<1, 256, 0, stream>>>(hdr, partials, xpart);
  k_quant_tern<<<QB_BLK + TB_BLK, 256, 0, stream>>>((const float4*)x, (const float4*)w,
                                                    (int*)qbuf, (int*)sbuf, hdr);
  k_gemm<<<(TOKENS / 256) * (OUT_F / 256), 512, 0, stream>>>(qbuf, sbuf, out);
}